// Round 1
// baseline (331.779 us; speedup 1.0000x reference)
//
#include <hip/hip_runtime.h>

// SCTC-SB loss: 560 independent CTC forward scans, one wave per (b,f) pair.
// Lane l holds extended states e=4l..4l+3 in registers; cross-lane neighbors
// via __shfl_up. No LDS, no barriers in the recursion.

#define NEGF (-1e30f)

constexpr int Bc = 16, Tc = 500, Sc = 100, Fc = 35;
constexpr int NPAIR = Bc * Fc;  // 560

__device__ __forceinline__ float lse2f(float a, float b) {
  float m = fmaxf(a, b);
  return m + logf(expf(a - m) + expf(b - m));
}

__device__ __forceinline__ float lse3f(float a, float b, float c) {
  float m = fmaxf(fmaxf(a, b), c);
  return m + logf(expf(a - m) + expf(b - m) + expf(c - m));
}

__global__ __launch_bounds__(256) void sctc_fwd(
    const float* __restrict__ logits,      // (B,T,F)
    const float* __restrict__ blank_logit, // (1,)
    const int* __restrict__ targets,       // (B,S,F) 0/1
    const int* __restrict__ in_len,        // (B,)
    const int* __restrict__ tgt_len,       // (B,)
    float* __restrict__ ws) {              // (B*F,) per-pair scaled loss
  const int wave = threadIdx.x >> 6;
  const int lane = threadIdx.x & 63;
  const int p = blockIdx.x * 4 + wave;
  if (p >= NPAIR) return;
  const int b = p / Fc, f = p % Fc;
  const int Tin = in_len[b];        // uniform per wave
  const int L = tgt_len[b];         // uniform per wave
  const float blank = blank_logit[0];

  // Per-lane target bits for odd states e=4l+1 (s=2l) and e=4l+3 (s=2l+1).
  const int s0 = 2 * lane, s1 = 2 * lane + 1;
  const int tbase = b * Sc * Fc + f;
  const int t0 = targets[tbase + min(s0, Sc - 1) * Fc];
  const int t1 = targets[tbase + min(s1, Sc - 1) * Fc];
  const int tprev = __shfl_up(t1, 1);  // tgt[2l-1]
  // allow_skip: odd states only; e=1 always allowed; else tgt[s] != tgt[s-1]
  const bool skip1 = (lane == 0) ? true : (t0 != tprev);
  const bool skip3 = (t1 != t0);

  float a0 = NEGF, a1 = NEGF, a2 = NEGF, a3 = NEGF;
  const float* lg = logits + b * Tc * Fc + f;

  for (int tc = 0; tc < Tin; tc += 64) {
    // one coalesced-ish scalar load per lane covers 64 timesteps
    const float xl = lg[min(tc + lane, Tc - 1) * Fc];
    const int jend = min(64, Tin - tc);
    for (int j = 0; j < jend; ++j) {
      const float x = __shfl(xl, j);
      // log_softmax over (-x, x, blank)
      const float m0 = fmaxf(fabsf(x), blank);
      const float ls =
          m0 + logf(expf(-x - m0) + expf(x - m0) + expf(blank - m0));
      const float lp0 = -x - ls;      // class 0 (absent)
      const float lp1 = x - ls;       // class 1 (present)
      const float lp2 = blank - ls;   // class 2 (blank)
      const float lpo0 = t0 ? lp1 : lp0;
      const float lpo1 = t1 ? lp1 : lp0;

      if (tc == 0 && j == 0) {
        // alpha init at t=0: only states 0 and 1 live
        if (lane == 0) { a0 = lp2; a1 = lpo0; }
        continue;
      }

      float prev3 = __shfl_up(a3, 1);  // alpha[4l-1]
      float prev2 = __shfl_up(a2, 1);  // alpha[4l-2]
      if (lane == 0) { prev3 = NEGF; prev2 = NEGF; }

      const float n0 = lse2f(a0, prev3) + lp2;                          // even: no skip
      const float n1 = lse3f(a1, a0, skip1 ? prev2 : NEGF) + lpo0;      // e=4l+1
      const float n2 = lse2f(a2, a1) + lp2;                             // even
      const float n3 = lse3f(a3, a2, skip3 ? a1 : NEGF) + lpo1;         // e=4l+3
      a0 = n0; a1 = n1; a2 = n2; a3 = n3;
    }
  }

  // final log-likelihood from states 2L and 2L-1
  const int e1 = 2 * L, e2 = 2 * L - 1;
  const float v1 = (e1 & 2) ? a2 : a0;  // e1 even -> idx 0 or 2
  const float v2 = (e2 & 2) ? a3 : a1;  // e2 odd  -> idx 1 or 3
  const float aL = __shfl(v1, e1 >> 2);
  const float aL1 = __shfl(v2, e2 >> 2);
  float loss = -lse2f(aL, aL1);
  if (loss > 0.5e30f) loss = 0.0f;  // zero_infinity
  const float val = loss / (float)L * (1.0f / (float)NPAIR);
  if (lane == 0) ws[p] = val;
}

__global__ __launch_bounds__(256) void sctc_reduce(const float* __restrict__ ws,
                                                   float* __restrict__ out) {
  const int tid = threadIdx.x;
  float s = 0.0f;
  for (int i = tid; i < NPAIR; i += 256) s += ws[i];
  for (int off = 32; off >= 1; off >>= 1) s += __shfl_down(s, off);
  __shared__ float partial[4];
  if ((tid & 63) == 0) partial[tid >> 6] = s;
  __syncthreads();
  if (tid == 0) out[0] = partial[0] + partial[1] + partial[2] + partial[3];
}

extern "C" void kernel_launch(void* const* d_in, const int* in_sizes, int n_in,
                              void* d_out, int out_size, void* d_ws, size_t ws_size,
                              hipStream_t stream) {
  const float* logits = (const float*)d_in[0];
  const float* blank_logit = (const float*)d_in[1];
  const int* targets = (const int*)d_in[2];
  const int* in_len = (const int*)d_in[3];
  const int* tgt_len = (const int*)d_in[4];
  float* ws = (float*)d_ws;
  float* out = (float*)d_out;

  const int grid = (NPAIR + 3) / 4;  // 4 waves (pairs) per 256-thread block
  sctc_fwd<<<grid, 256, 0, stream>>>(logits, blank_logit, targets, in_len,
                                     tgt_len, ws);
  sctc_reduce<<<1, 256, 0, stream>>>(ws, out);
}

// Round 2
// 116.677 us; speedup vs baseline: 2.8436x; 2.8436x over previous
//
#include <hip/hip_runtime.h>

// SCTC-SB loss: 560 independent CTC forward scans, one wave per (b,f) pair.
// Lane l holds extended states e=4l..4l+3 in registers.
// Round-1 changes: log-softmax hoisted out of serial loop (per-lane per-chunk,
// broadcast via v_readlane); __shfl_up -> DPP wave_shr:1; base-2 log domain.

#define NEGF (-1e30f)
#define LOG2E 1.4426950408889634f
#define LN2 0.6931471805599453f

constexpr int Bc = 16, Tc = 500, Sc = 100, Fc = 35;
constexpr int NPAIR = Bc * Fc;  // 560

// lane l gets lane l-1's value; lane 0 gets `fill`. Single VALU op (DPP).
__device__ __forceinline__ float dpp_shr1(float v, float fill) {
  int r = __builtin_amdgcn_update_dpp(__float_as_int(fill), __float_as_int(v),
                                      0x138 /*wave_shr:1*/, 0xF, 0xF, false);
  return __int_as_float(r);
}

// log2-domain LSE: log2(2^a + 2^b)
__device__ __forceinline__ float lse2_2(float a, float b) {
  float m = fmaxf(a, b);
  float e = exp2f(-fabsf(a - b));  // -|d| folds into exp input modifier
  return m + log2f(1.0f + e);
}

// log2-domain LSE3: log2(2^a + 2^b + 2^c)
__device__ __forceinline__ float lse3_2(float a, float b, float c) {
  float m = fmaxf(fmaxf(a, b), c);  // v_max3_f32
  return m + log2f(exp2f(a - m) + exp2f(b - m) + exp2f(c - m));
}

__device__ __forceinline__ void ctc_step(float& a0, float& a1, float& a2,
                                         float& a3, float xs, float ss,
                                         float blank2, int t0, int t1,
                                         bool skip1, bool skip3) {
  // xs, ss are wave-uniform (readlane -> SGPR)
  const float lp2 = blank2 - ss;
  const float lp0 = -xs - ss;
  const float lp1 = xs - ss;
  const float lpo0 = t0 ? lp1 : lp0;
  const float lpo1 = t1 ? lp1 : lp0;
  const float prev3 = dpp_shr1(a3, NEGF);  // alpha[4l-1]
  const float prev2 = dpp_shr1(a2, NEGF);  // alpha[4l-2]
  const float n0 = lse2_2(a0, prev3) + lp2;
  const float n1 = lse3_2(a1, a0, skip1 ? prev2 : NEGF) + lpo0;
  const float n2 = lse2_2(a2, a1) + lp2;
  const float n3 = lse3_2(a3, a2, skip3 ? a1 : NEGF) + lpo1;
  a0 = n0; a1 = n1; a2 = n2; a3 = n3;
}

__device__ __forceinline__ float rdlane(float v, int j) {
  return __int_as_float(__builtin_amdgcn_readlane(__float_as_int(v), j));
}

__global__ __launch_bounds__(256) void sctc_fwd(
    const float* __restrict__ logits,       // (B,T,F)
    const float* __restrict__ blank_logit,  // (1,)
    const int* __restrict__ targets,        // (B,S,F) 0/1
    const int* __restrict__ in_len,         // (B,)
    const int* __restrict__ tgt_len,        // (B,)
    float* __restrict__ ws) {               // (B*F,)
  const int wave = threadIdx.x >> 6;
  const int lane = threadIdx.x & 63;
  const int p = blockIdx.x * 4 + wave;
  if (p >= NPAIR) return;
  const int b = p / Fc, f = p % Fc;
  const int Tin = in_len[b];  // uniform per wave
  const int L = tgt_len[b];   // uniform per wave
  const float blank2 = blank_logit[0] * LOG2E;

  // Per-lane target bits for odd states e=4l+1 (s=2l) and e=4l+3 (s=2l+1).
  const int s0 = 2 * lane, s1 = 2 * lane + 1;
  const int tbase = b * Sc * Fc + f;
  const int t0 = targets[tbase + min(s0, Sc - 1) * Fc];
  const int t1 = targets[tbase + min(s1, Sc - 1) * Fc];
  const int tprev = __shfl_up(t1, 1);  // tgt[2l-1] (init only, off hot path)
  const bool skip1 = (lane == 0) ? true : (t0 != tprev);
  const bool skip3 = (t1 != t0);

  float a0 = NEGF, a1 = NEGF, a2 = NEGF, a3 = NEGF;
  const float* lg = logits + b * Tc * Fc + f;

  // t = 0 init: only states 0,1 live
  {
    const float x0 = lg[0] * LOG2E;  // uniform broadcast load
    const float m0 = fmaxf(fabsf(x0), blank2);
    const float ls =
        m0 + log2f(exp2f(-x0 - m0) + exp2f(x0 - m0) + exp2f(blank2 - m0));
    if (lane == 0) {
      a0 = blank2 - ls;
      a1 = (t0 ? x0 : -x0) - ls;
    }
  }

  // chunks of 64 timesteps: lane j owns t = tb + j
  float xraw = lg[min(1 + lane, Tc - 1) * Fc];
  for (int tb = 1; tb < Tin; tb += 64) {
    // prefetch next chunk
    float xnextraw = 0.0f;
    if (tb + 64 < Tin) xnextraw = lg[min(tb + 64 + lane, Tc - 1) * Fc];

    // per-lane log-softmax for this lane's timestep (base-2 domain)
    const float x = xraw * LOG2E;
    const float m0 = fmaxf(fabsf(x), blank2);
    const float ls =
        m0 + log2f(exp2f(-x - m0) + exp2f(x - m0) + exp2f(blank2 - m0));

    const int n = min(64, Tin - tb);
    if (n == 64) {
#pragma unroll 8
      for (int j = 0; j < 64; ++j) {
        ctc_step(a0, a1, a2, a3, rdlane(x, j), rdlane(ls, j), blank2, t0, t1,
                 skip1, skip3);
      }
    } else {
      for (int j = 0; j < n; ++j) {
        ctc_step(a0, a1, a2, a3, rdlane(x, j), rdlane(ls, j), blank2, t0, t1,
                 skip1, skip3);
      }
    }
    xraw = xnextraw;
  }

  // final log-likelihood from states 2L and 2L-1 (log2 domain)
  const int e1 = 2 * L, e2 = 2 * L - 1;
  const float v1 = (e1 & 2) ? a2 : a0;  // even state -> reg 0 or 2
  const float v2 = (e2 & 2) ? a3 : a1;  // odd state  -> reg 1 or 3
  const float aL = __shfl(v1, e1 >> 2);
  const float aL1 = __shfl(v2, e2 >> 2);
  float loss = -lse2_2(aL, aL1) * LN2;
  if (loss > 0.5e30f) loss = 0.0f;  // zero_infinity
  const float val = loss / (float)L * (1.0f / (float)NPAIR);
  if (lane == 0) ws[p] = val;
}

__global__ __launch_bounds__(256) void sctc_reduce(const float* __restrict__ ws,
                                                   float* __restrict__ out) {
  const int tid = threadIdx.x;
  float s = 0.0f;
  for (int i = tid; i < NPAIR; i += 256) s += ws[i];
  for (int off = 32; off >= 1; off >>= 1) s += __shfl_down(s, off);
  __shared__ float partial[4];
  if ((tid & 63) == 0) partial[tid >> 6] = s;
  __syncthreads();
  if (tid == 0) out[0] = partial[0] + partial[1] + partial[2] + partial[3];
}

extern "C" void kernel_launch(void* const* d_in, const int* in_sizes, int n_in,
                              void* d_out, int out_size, void* d_ws,
                              size_t ws_size, hipStream_t stream) {
  const float* logits = (const float*)d_in[0];
  const float* blank_logit = (const float*)d_in[1];
  const int* targets = (const int*)d_in[2];
  const int* in_len = (const int*)d_in[3];
  const int* tgt_len = (const int*)d_in[4];
  float* ws = (float*)d_ws;
  float* out = (float*)d_out;

  const int grid = (NPAIR + 3) / 4;  // 4 waves (pairs) per 256-thread block
  sctc_fwd<<<grid, 256, 0, stream>>>(logits, blank_logit, targets, in_len,
                                     tgt_len, ws);
  sctc_reduce<<<1, 256, 0, stream>>>(ws, out);
}

// Round 4
// 58.233 us; speedup vs baseline: 5.6974x; 2.0036x over previous
//
#include <hip/hip_runtime.h>
#include <math.h>

// SCTC-SB loss, round 3 (= round-2 design + DPP-ctrl-as-template compile fix):
// fp64 LINEAR-domain forward recursion (no per-step transcendentals).
// One wave per (b,f); lane l holds states 4l..4l+3.
// Renorm every 32 steps: band-masked exponent max via DPP, rescale to 2^400,
// integer log2 offset. fp64 range (>1000 nats) covers worst path spread.

#define LOG2E 1.4426950408889634f
#define LN2d 0.69314718055994530942

constexpr int Bc = 16, Tc = 500, Sc = 100, Fc = 35;
constexpr int NPAIR = Bc * Fc;  // 560
constexpr int EXPT = 400;       // renorm target exponent (unbiased)

// lane l gets lane l-1's value; lane 0 gets 0.0 (= -inf in linear domain)
__device__ __forceinline__ double dpp_shr1_d(double v) {
  int lo = __builtin_amdgcn_update_dpp(0, __double2loint(v),
                                       0x138 /*wave_shr1*/, 0xF, 0xF, false);
  int hi = __builtin_amdgcn_update_dpp(0, __double2hiint(v), 0x138,
                                       0xF, 0xF, false);
  return __hiloint2double(hi, lo);
}

__device__ __forceinline__ double rdlane_d(double v, int j) {
  int lo = __builtin_amdgcn_readlane(__double2loint(v), j);
  int hi = __builtin_amdgcn_readlane(__double2hiint(v), j);
  return __hiloint2double(hi, lo);
}

template <int CTRL>
__device__ __forceinline__ int dpp_max_i(int v) {
  int t = __builtin_amdgcn_update_dpp(v, v, CTRL, 0xF, 0xF, false);
  return max(v, t);
}

__global__ __launch_bounds__(256) void sctc_fwd(
    const float* __restrict__ logits,       // (B,T,F)
    const float* __restrict__ blank_logit,  // (1,)
    const int* __restrict__ targets,        // (B,S,F) 0/1
    const int* __restrict__ in_len,         // (B,)
    const int* __restrict__ tgt_len,        // (B,)
    float* __restrict__ ws) {               // (B*F,)
  const int wave = threadIdx.x >> 6;
  const int lane = threadIdx.x & 63;
  const int p = blockIdx.x * 4 + wave;
  if (p >= NPAIR) return;
  const int b = p / Fc, f = p % Fc;
  const int Tin = in_len[b];  // uniform per wave
  const int L = tgt_len[b];   // uniform per wave
  const float b2 = blank_logit[0] * LOG2E;

  // Per-lane target bits for odd states e=4l+1 (s=2l) and e=4l+3 (s=2l+1).
  const int tbase = b * Sc * Fc + f;
  const int t0 = targets[tbase + min(2 * lane, Sc - 1) * Fc];
  const int t1 = targets[tbase + min(2 * lane + 1, Sc - 1) * Fc];
  const int tprev = __shfl_up(t1, 1);  // tgt[2l-1] (init only)
  const bool bt0 = (t0 != 0), bt1 = (t1 != 0);
  const double sk1 = (lane == 0 || t0 != tprev) ? 1.0 : 0.0;
  const double sk3 = (t1 != t0) ? 1.0 : 0.0;

  const int e_hi = 2 * L + 1;  // band upper cap (readout needs 2L-1, 2L)
  const bool h0 = (4 * lane) <= e_hi, h1 = (4 * lane + 1) <= e_hi,
             h2 = (4 * lane + 2) <= e_hi, h3 = (4 * lane + 3) <= e_hi;

  double a0 = 0.0, a1 = 0.0, a2 = 0.0, a3 = 0.0;
  int off = -EXPT;  // true_alpha = stored * 2^off ; ll_log2 = log2(stored)+off
  const float* lg = logits + b * Tc * Fc + f;

  // t = 0 init: only states 0,1 live
  {
    const float x0 = lg[0] * LOG2E;
    const float m0 = fmaxf(fabsf(x0), b2);
    const float u0 = exp2f(-x0 - m0), u1 = exp2f(x0 - m0), u2 = exp2f(b2 - m0);
    const float rz = 1.0f / (u0 + u1 + u2);
    if (lane == 0) {
      a0 = ldexp((double)(u2 * rz), EXPT);
      a1 = ldexp((double)((bt0 ? u1 : u0) * rz), EXPT);
    }
  }

  float xraw = lg[min(1 + lane, Tc - 1) * Fc];
  for (int tb = 1; tb < Tin; tb += 64) {
    float xnext = 0.0f;
    if (tb + 64 < Tin) xnext = lg[min(tb + 64 + lane, Tc - 1) * Fc];

    // per-lane 3-class softmax (lane j owns t = tb + j), fp32 -> fp64
    const float t2 = xraw * LOG2E;
    const float m0 = fmaxf(fabsf(t2), b2);
    const float u0 = exp2f(-t2 - m0), u1 = exp2f(t2 - m0), u2 = exp2f(b2 - m0);
    const float rz = 1.0f / (u0 + u1 + u2);
    const double p0d = (double)(u0 * rz);
    const double p1d = (double)(u1 * rz);
    const double p2d = (double)(u2 * rz);

    const int n = min(64, Tin - tb);
    for (int g = 0; g < n; g += 32) {
      const int gn = min(32, n - g);
#pragma unroll 8
      for (int j = 0; j < gn; ++j) {
        const double q0 = rdlane_d(p0d, g + j);
        const double q1 = rdlane_d(p1d, g + j);
        const double q2 = rdlane_d(p2d, g + j);
        const double po0 = bt0 ? q1 : q0;
        const double po1 = bt1 ? q1 : q0;
        const double pr3 = dpp_shr1_d(a3);  // alpha[4l-1]
        const double pr2 = dpp_shr1_d(a2);  // alpha[4l-2]
        const double n0 = (a0 + pr3) * q2;
        const double n1 = fma(pr2, sk1, a0 + a1) * po0;
        const double n2 = (a2 + a1) * q2;
        const double n3 = fma(a1, sk3, a3 + a2) * po1;
        a0 = n0; a1 = n1; a2 = n2; a3 = n3;
      }
      // ---- renorm (every <=32 steps). tt = last processed time index.
      const int tt = tb + g + gn - 1;
      const int elo = max(0, (2 * L - 1) - 2 * (Tin - 1 - tt));
      // band-masked biased exponents (alpha >= 0 so hi>>20 is the exponent)
      const int ex0 = (h0 && (4 * lane) >= elo)
                          ? ((__double2hiint(a0) >> 20) & 0x7ff) : -100000;
      const int ex1 = (h1 && (4 * lane + 1) >= elo)
                          ? ((__double2hiint(a1) >> 20) & 0x7ff) : -100000;
      const int ex2 = (h2 && (4 * lane + 2) >= elo)
                          ? ((__double2hiint(a2) >> 20) & 0x7ff) : -100000;
      const int ex3 = (h3 && (4 * lane + 3) >= elo)
                          ? ((__double2hiint(a3) >> 20) & 0x7ff) : -100000;
      int m = max(max(ex0, ex1), max(ex2, ex3));
      m = dpp_max_i<0x111>(m);  // row_shr:1
      m = dpp_max_i<0x112>(m);  // row_shr:2
      m = dpp_max_i<0x114>(m);  // row_shr:4
      m = dpp_max_i<0x118>(m);  // row_shr:8
      m = dpp_max_i<0x142>(m);  // row_bcast15
      m = dpp_max_i<0x143>(m);  // row_bcast31
      const int mw = __builtin_amdgcn_readlane(m, 63);  // biased band max exp
      int k = (EXPT + 1023) - mw;
      k = min(max(k, -1000), 1000);
      const double scale = __hiloint2double((k + 1023) << 20, 0);  // 2^k
      a0 *= scale; a1 *= scale; a2 *= scale; a3 *= scale;
      off -= k;
    }
    xraw = xnext;
  }

  // readout: ll = log(alpha[2L] + alpha[2L-1])
  const int e1 = 2 * L, e2 = 2 * L - 1;
  const double v1 = (e1 & 2) ? a2 : a0;  // even state -> reg 0 or 2
  const double v2 = (e2 & 2) ? a3 : a1;  // odd state  -> reg 1 or 3
  const double aL = rdlane_d(v1, e1 >> 2);
  const double aL1 = rdlane_d(v2, e2 >> 2);
  const double s = aL + aL1;
  double lossd;
  if (s > 0.0) {
    int ex;
    const double mant = frexp(s, &ex);  // s = mant * 2^ex, mant in [0.5,1)
    const double ll2 = (double)(ex + off) + (double)log2f((float)mant);
    lossd = -ll2 * LN2d;
    if (lossd > 0.5e30) lossd = 0.0;  // zero_infinity
  } else {
    lossd = 0.0;  // alpha underflowed to 0 => loss = +inf => zeroed
  }
  const float val = (float)(lossd / (double)L) * (1.0f / (float)NPAIR);
  if (lane == 0) ws[p] = val;
}

__global__ __launch_bounds__(256) void sctc_reduce(const float* __restrict__ ws,
                                                   float* __restrict__ out) {
  const int tid = threadIdx.x;
  float s = 0.0f;
  for (int i = tid; i < NPAIR; i += 256) s += ws[i];
  for (int off = 32; off >= 1; off >>= 1) s += __shfl_down(s, off);
  __shared__ float partial[4];
  if ((tid & 63) == 0) partial[tid >> 6] = s;
  __syncthreads();
  if (tid == 0) out[0] = partial[0] + partial[1] + partial[2] + partial[3];
}

extern "C" void kernel_launch(void* const* d_in, const int* in_sizes, int n_in,
                              void* d_out, int out_size, void* d_ws,
                              size_t ws_size, hipStream_t stream) {
  const float* logits = (const float*)d_in[0];
  const float* blank_logit = (const float*)d_in[1];
  const int* targets = (const int*)d_in[2];
  const int* in_len = (const int*)d_in[3];
  const int* tgt_len = (const int*)d_in[4];
  float* ws = (float*)d_ws;
  float* out = (float*)d_out;

  const int grid = (NPAIR + 3) / 4;  // 4 waves (pairs) per 256-thread block
  sctc_fwd<<<grid, 256, 0, stream>>>(logits, blank_logit, targets, in_len,
                                     tgt_len, ws);
  sctc_reduce<<<1, 256, 0, stream>>>(ws, out);
}

// Round 5
// 36.047 us; speedup vs baseline: 9.2041x; 1.6155x over previous
//
#include <hip/hip_runtime.h>
#include <math.h>

// SCTC-SB loss, round 5:
//  - BUGFIX: skip source for state 4l+1 is alpha[4l-1] = prev lane's a3 (pr3),
//    not prev lane's a2. (All prior rounds had this wrong; absmax 0.094 was
//    this bug.) Also means only ONE cross-lane value per step.
//  - fp32 LINEAR-domain recursion (was fp64): renorm every 8 steps to 2^110,
//    band-masked exponent max via DPP. In-band spread budget ~163 nats.
//  - fully static unroll-64 chunks -> immediate-lane v_readlane, deep
//    cross-step scheduling; wave-uniform checked variant for boundary chunk.

#define LOG2E 1.4426950408889634f
#define LN2d 0.69314718055994530942

constexpr int Bc = 16, Tc = 500, Sc = 100, Fc = 35;
constexpr int NPAIR = Bc * Fc;  // 560
constexpr int EXPB = 237;       // renorm target biased exponent (2^110)

// lane l gets lane l-1's value; lane 0 gets 0.0f
__device__ __forceinline__ float dpp_shr1(float v) {
  return __int_as_float(__builtin_amdgcn_update_dpp(
      0, __float_as_int(v), 0x138 /*wave_shr:1*/, 0xF, 0xF, false));
}
__device__ __forceinline__ float rdl(float v, int j) {
  return __int_as_float(__builtin_amdgcn_readlane(__float_as_int(v), j));
}
template <int C>
__device__ __forceinline__ int dppmax(int v) {
  int t = __builtin_amdgcn_update_dpp(v, v, C, 0xF, 0xF, false);
  return max(v, t);
}

__global__ __launch_bounds__(256) void sctc_fwd(
    const float* __restrict__ logits,       // (B,T,F)
    const float* __restrict__ blank_logit,  // (1,)
    const int* __restrict__ targets,        // (B,S,F) 0/1
    const int* __restrict__ in_len,         // (B,)
    const int* __restrict__ tgt_len,        // (B,)
    float* __restrict__ ws) {               // (B*F,)
  const int wave = threadIdx.x >> 6;
  const int lane = threadIdx.x & 63;
  const int p = blockIdx.x * 4 + wave;
  if (p >= NPAIR) return;
  const int b = p / Fc, f = p % Fc;
  const int Tin = in_len[b];  // uniform per wave
  const int L = tgt_len[b];   // uniform per wave
  const float b2 = blank_logit[0] * LOG2E;

  // lane l holds states e = 4l..4l+3 as a0..a3.
  // odd states: 4l+1 <-> target s=2l (bit t0), 4l+3 <-> s=2l+1 (bit t1)
  const int tbase = b * Sc * Fc + f;
  const int t0 = targets[tbase + min(2 * lane, Sc - 1) * Fc];
  const int t1 = targets[tbase + min(2 * lane + 1, Sc - 1) * Fc];
  const int tprev = __shfl_up(t1, 1);  // tgt[2l-1] (init only)
  const bool bt0 = (t0 != 0), bt1 = (t1 != 0);
  const bool sk1 = (lane == 0) || (t0 != tprev);  // skip into 4l+1 from 4l-1
  const bool sk3 = (t1 != t0);                    // skip into 4l+3 from 4l+1

  const int e_hi = 2 * L + 1;     // band upper cap
  const int twoLm1 = 2 * L - 1;   // readout lower state
  const int e0 = 4 * lane, e1c = e0 + 1, e2c = e0 + 2, e3c = e0 + 3;
  const bool in0 = e0 <= e_hi, in1 = e1c <= e_hi, in2 = e2c <= e_hi,
             in3 = e3c <= e_hi;

  float a0 = 0.0f, a1 = 0.0f, a2 = 0.0f, a3 = 0.0f;
  int off = -110;  // true_alpha = stored * 2^off
  const float* lg = logits + b * Tc * Fc + f;

  // t = 0 init: only states 0,1 live
  {
    const float x0 = lg[0] * LOG2E;
    const float m0 = fmaxf(fabsf(x0), b2);
    const float u0 = exp2f(-x0 - m0), u1 = exp2f(x0 - m0), u2 = exp2f(b2 - m0);
    const float rz = 1.0f / (u0 + u1 + u2);
    if (lane == 0) {
      a0 = ldexpf(u2 * rz, 110);
      a1 = ldexpf((bt0 ? u1 : u0) * rz, 110);
    }
  }

#define STEP(J)                                                        \
  {                                                                    \
    const float q0 = rdl(p0, (J)), q1 = rdl(p1, (J)), q2 = rdl(p2, (J)); \
    const float po0 = bt0 ? q1 : q0;                                   \
    const float po1 = bt1 ? q1 : q0;                                   \
    const float pr3 = dpp_shr1(a3); /* alpha[4l-1] */                  \
    const float m1 = sk1 ? pr3 : 0.0f;                                 \
    const float m3 = sk3 ? a1 : 0.0f;                                  \
    const float s01 = a0 + a1, s12 = a1 + a2, s23 = a2 + a3;           \
    a0 = (a0 + pr3) * q2;                                              \
    a1 = (s01 + m1) * po0;                                             \
    a2 = s12 * q2;                                                     \
    a3 = (s23 + m3) * po1;                                             \
  }

#define RENORM(TT)                                                        \
  {                                                                       \
    const int elo = twoLm1 - 2 * (Tin - 1 - (TT));                        \
    int ex0 = (in0 && e0 >= elo) ? (__float_as_int(a0) >> 23) : 0;        \
    int ex1 = (in1 && e1c >= elo) ? (__float_as_int(a1) >> 23) : 0;       \
    int ex2 = (in2 && e2c >= elo) ? (__float_as_int(a2) >> 23) : 0;       \
    int ex3 = (in3 && e3c >= elo) ? (__float_as_int(a3) >> 23) : 0;       \
    int mm = max(max(ex0, ex1), max(ex2, ex3));                           \
    mm = dppmax<0x111>(mm);                                               \
    mm = dppmax<0x112>(mm);                                               \
    mm = dppmax<0x114>(mm);                                               \
    mm = dppmax<0x118>(mm);                                               \
    mm = dppmax<0x142>(mm);                                               \
    mm = dppmax<0x143>(mm);                                               \
    const int mw = __builtin_amdgcn_readlane(mm, 63);                     \
    int k = EXPB - mw;                                                    \
    k = min(k, 126);                                                      \
    const float sc = __int_as_float((k + 127) << 23);                     \
    a0 *= sc; a1 *= sc; a2 *= sc; a3 *= sc;                               \
    off -= k;                                                             \
  }

  float xraw = lg[min(1 + lane, Tc - 1) * Fc];
  for (int tb = 1; tb < Tc; tb += 64) {
    if (tb >= Tin) break;
    float xnext = 0.0f;
    if (tb + 64 < Tin) xnext = lg[min(tb + 64 + lane, Tc - 1) * Fc];

    // per-lane 3-class softmax: lane j owns t = tb + j
    const float xx = xraw * LOG2E;
    const float m0 = fmaxf(fabsf(xx), b2);
    const float u0 = exp2f(-xx - m0), u1 = exp2f(xx - m0), u2 = exp2f(b2 - m0);
    const float rz = 1.0f / (u0 + u1 + u2);
    const float p0 = u0 * rz, p1 = u1 * rz, p2 = u2 * rz;

    if (tb + 63 < Tin) {
#pragma unroll
      for (int j = 0; j < 64; ++j) {
        STEP(j);
        if ((j & 7) == 7) RENORM(tb + j);
      }
    } else {
#pragma unroll
      for (int j = 0; j < 64; ++j) {
        if (tb + j >= Tin) break;  // wave-uniform
        STEP(j);
        if ((j & 7) == 7) RENORM(tb + j);
      }
    }
    xraw = xnext;
  }

  // readout: ll = log(alpha[2L] + alpha[2L-1]) + off*ln2
  const int r1 = 2 * L, r2 = 2 * L - 1;
  const float w1 = (r1 & 2) ? a2 : a0;  // even state -> reg 0 or 2
  const float w2 = (r2 & 2) ? a3 : a1;  // odd state  -> reg 1 or 3
  const float aL = rdl(w1, r1 >> 2);
  const float aL1 = rdl(w2, r2 >> 2);
  const float ssum = aL + aL1;
  float val;
  if (ssum > 0.0f) {
    const int bits = __float_as_int(ssum);
    const int ex = ((bits >> 23) & 255) - 126;
    const float mant = __int_as_float((bits & 0x007fffff) | 0x3f000000);
    const double ll2 = (double)(ex + off) + (double)log2f(mant);
    double ld = -ll2 * LN2d;
    if (ld > 0.5e30) ld = 0.0;  // zero_infinity
    val = (float)(ld / (double)L) * (1.0f / (float)NPAIR);
  } else {
    val = 0.0f;  // underflow => inf loss => zeroed
  }
  if (lane == 0) ws[p] = val;
#undef STEP
#undef RENORM
}

__global__ __launch_bounds__(256) void sctc_reduce(const float* __restrict__ ws,
                                                   float* __restrict__ out) {
  const int tid = threadIdx.x;
  float s = 0.0f;
  for (int i = tid; i < NPAIR; i += 256) s += ws[i];
  for (int off = 32; off >= 1; off >>= 1) s += __shfl_down(s, off);
  __shared__ float partial[4];
  if ((tid & 63) == 0) partial[tid >> 6] = s;
  __syncthreads();
  if (tid == 0) out[0] = partial[0] + partial[1] + partial[2] + partial[3];
}

extern "C" void kernel_launch(void* const* d_in, const int* in_sizes, int n_in,
                              void* d_out, int out_size, void* d_ws,
                              size_t ws_size, hipStream_t stream) {
  const float* logits = (const float*)d_in[0];
  const float* blank_logit = (const float*)d_in[1];
  const int* targets = (const int*)d_in[2];
  const int* in_len = (const int*)d_in[3];
  const int* tgt_len = (const int*)d_in[4];
  float* ws = (float*)d_ws;
  float* out = (float*)d_out;

  const int grid = (NPAIR + 3) / 4;  // 4 waves (pairs) per 256-thread block
  sctc_fwd<<<grid, 256, 0, stream>>>(logits, blank_logit, targets, in_len,
                                     tgt_len, ws);
  sctc_reduce<<<1, 256, 0, stream>>>(ws, out);
}